// Round 4
// baseline (730.008 us; speedup 1.0000x reference)
//
#include <hip/hip_runtime.h>
#include <hip/hip_bf16.h>

// Problem dims
#define BB 8
#define FF 512
#define SS 8192
#define HH 8
#define DD 64
#define N1 1536   // 3*H*D qkv output columns

typedef __hip_bfloat16 bf16;
typedef __attribute__((ext_vector_type(8))) short bf16x8;
typedef __attribute__((ext_vector_type(4))) float f32x4;

__device__ __forceinline__ float us2f(unsigned short u) {
    union { unsigned int i; float f; } x; x.i = ((unsigned int)u) << 16; return x.f;
}
__device__ __forceinline__ unsigned short f2b(float f) {
    unsigned int u = __builtin_bit_cast(unsigned int, f);
    return (unsigned short)((u + 0x7FFFu + ((u >> 16) & 1u)) >> 16);   // RNE
}
__device__ __forceinline__ void gll16(const void* g, void* l) {
    __builtin_amdgcn_global_load_lds((const __attribute__((address_space(1))) void*)g,
                                     (__attribute__((address_space(3))) void*)l, 16, 0, 0);
}
// BK=32 tile: [128 rows][32 bf16], row stride 64B; rotated k-chunk swizzle
__device__ __forceinline__ bf16x8 fragld(const unsigned short* base, int row, int quad) {
    int off = row * 32 + (((quad + (row >> 1)) & 3) << 3);
    return *(const bf16x8*)(base + off);
}

// ---------------------------------------------------------------------------
// GN1 partial stats: grid (256 bg, 8 s-chunks); atomicAdd fp32 partials
__global__ void gn1_part(const float* __restrict__ hid, float* __restrict__ part) {
    int bg = blockIdx.x;
    const float4* base = (const float4*)(hid + ((size_t)(bg >> 5) * FF + (bg & 31) * 16) * SS);
    float s = 0.f, s2 = 0.f;
    int t0 = blockIdx.y * 4096 + threadIdx.x;
    #pragma unroll
    for (int it = 0; it < 16; it++) {
        float4 x = base[t0 + it * 256];
        s  += x.x + x.y + x.z + x.w;
        s2 += x.x * x.x + x.y * x.y + x.z * x.z + x.w * x.w;
    }
    #pragma unroll
    for (int off = 32; off > 0; off >>= 1) {
        s  += __shfl_down(s, off, 64);
        s2 += __shfl_down(s2, off, 64);
    }
    __shared__ float rs_[8];
    int wid = threadIdx.x >> 6, lane = threadIdx.x & 63;
    if (lane == 0) { rs_[wid] = s; rs_[wid + 4] = s2; }
    __syncthreads();
    if (threadIdx.x == 0)
        atomicAdd(&part[bg * 2], rs_[0] + rs_[1] + rs_[2] + rs_[3]);
    else if (threadIdx.x == 64)
        atomicAdd(&part[bg * 2 + 1], rs_[4] + rs_[5] + rs_[6] + rs_[7]);
}

// finalize: per-channel sc/sh (gate==nullptr for GN1; gate folded for GN2)
__global__ void gn_final(const float* __restrict__ part, const float* __restrict__ gamma,
                         const float* __restrict__ beta, const float* __restrict__ gate,
                         float* __restrict__ sc, float* __restrict__ sh) {
    int c = blockIdx.x * 256 + threadIdx.x;    // 0..4095  (b*512 + ch)
    int ch = c & 511;
    int bg = (c >> 9) * 32 + (ch >> 4);
    float ts = part[bg * 2], ts2 = part[bg * 2 + 1];
    float mu  = ts * (1.f / 131072.f);
    float var = ts2 * (1.f / 131072.f) - mu * mu;
    float r   = rsqrtf(var + 1e-8f);
    float scv = gamma[ch] * r;
    float shv = beta[ch] - mu * scv;
    if (gate) { float gv = gate[ch]; scv *= gv; shv *= gv; }
    sc[c] = scv; sh[c] = shv;
}

// ---------------------------------------------------------------------------
// elementwise fp32 -> bf16 cast (vectorized x4)
__global__ void castb(const float* __restrict__ s, unsigned short* __restrict__ d, int n4) {
    int i = blockIdx.x * 256 + threadIdx.x;
    if (i >= n4) return;
    float4 v = ((const float4*)s)[i];
    ushort4 u = make_ushort4(f2b(v.x), f2b(v.y), f2b(v.z), f2b(v.w));
    ((ushort4*)d)[i] = u;
}

// ---------------------------------------------------------------------------
// xn_prep: xnA[b][l][f] = bf16( hid[b][f][l]*sc + sh )  (transpose via LDS)
__global__ void xn_prep(const float* __restrict__ hid, const float* __restrict__ sc,
                        const float* __restrict__ sh, unsigned short* __restrict__ xnA) {
    int b = blockIdx.z, f0 = blockIdx.y * 64, l0 = blockIdx.x * 64;
    __shared__ float t[64][65];
    int tid = threadIdx.x;
    #pragma unroll
    for (int it = 0; it < 16; it++) {
        int idx = it * 256 + tid;
        int f = idx >> 6, l = idx & 63;
        int fg = f0 + f;
        t[f][l] = hid[((size_t)b * FF + fg) * SS + l0 + l] * sc[b * FF + fg] + sh[b * FF + fg];
    }
    __syncthreads();
    #pragma unroll
    for (int it = 0; it < 4; it++) {
        int idx = it * 256 + tid;
        int l = idx >> 4, fq = (idx & 15) * 4;
        ushort4 u = make_ushort4(f2b(t[fq + 0][l]), f2b(t[fq + 1][l]),
                                 f2b(t[fq + 2][l]), f2b(t[fq + 3][l]));
        *(ushort4*)(xnA + ((size_t)b * SS + l0 + l) * FF + f0 + fq) = u;
    }
}

// ---------------------------------------------------------------------------
// GEMM1, BK=32, 16 K-steps.
// KV=0: q blocks (n0 = y*128, y<4), swapped MFMA -> D[n][m];
//       staged [m][n] tile (ushort4 writes) -> 256B-row stores into q[B,S,F].
// KV=1: k/v blocks (n0 = 512 + y*128), normal MFMA -> D[m][n];
//       staged [n][m] tile (ushort4 writes) -> 256B-row stores into kT/vT[B,H,D,S].
template<int KV>
__global__ __launch_bounds__(256) void gemm1_mfma(
    const unsigned short* __restrict__ A, const unsigned short* __restrict__ Bw,
    const float* __restrict__ bias,
    unsigned short* __restrict__ q, unsigned short* __restrict__ kT,
    unsigned short* __restrict__ vT) {
    __shared__ unsigned short smem[16384] __attribute__((aligned(16)));  // 32KB
    unsigned short* As = smem;            // 128 x 32
    unsigned short* Bs = smem + 4096;
    const int b = blockIdx.z;
    const int m0 = blockIdx.x * 128;
    const int n0 = (KV ? 512 : 0) + blockIdx.y * 128;
    const int tid = threadIdx.x;
    const int w = tid >> 6, ln = tid & 63;
    const int wr = w >> 1, wc = w & 1;
    const int lrow = ln & 15, quad = ln >> 4;

    const int ch0 = tid, ch1 = tid + 256;
    const int ra = ch0 >> 2, ca = ((ch0 & 3) - (ra >> 1)) & 3;
    const int rb = ch1 >> 2, cb = ((ch1 & 3) - (rb >> 1)) & 3;
    const unsigned short* pA0 = A + ((size_t)b * SS + m0 + ra) * FF + ca * 8;
    const unsigned short* pA1 = A + ((size_t)b * SS + m0 + rb) * FF + cb * 8;
    const unsigned short* pB0 = Bw + (size_t)(n0 + ra) * FF + ca * 8;
    const unsigned short* pB1 = Bw + (size_t)(n0 + rb) * FF + cb * 8;
    unsigned short* lA0 = As + ch0 * 8; unsigned short* lA1 = As + ch1 * 8;
    unsigned short* lB0 = Bs + ch0 * 8; unsigned short* lB1 = Bs + ch1 * 8;

    f32x4 acc[4][4];
    #pragma unroll
    for (int j = 0; j < 4; j++)
        #pragma unroll
        for (int i = 0; i < 4; i++) acc[j][i] = (f32x4){0.f, 0.f, 0.f, 0.f};

    for (int kk = 0; kk < 16; kk++) {
        gll16(pA0, lA0); gll16(pA1, lA1); gll16(pB0, lB0); gll16(pB1, lB1);
        pA0 += 32; pA1 += 32; pB0 += 32; pB1 += 32;
        __syncthreads();
        bf16x8 af[4], bm[4];
        #pragma unroll
        for (int j = 0; j < 4; j++) af[j] = fragld(Bs, wc * 64 + j * 16 + lrow, quad);
        #pragma unroll
        for (int i = 0; i < 4; i++) bm[i] = fragld(As, wr * 64 + i * 16 + lrow, quad);
        if constexpr (KV == 0) {
            #pragma unroll
            for (int j = 0; j < 4; j++)
                #pragma unroll
                for (int i = 0; i < 4; i++)
                    acc[j][i] = __builtin_amdgcn_mfma_f32_16x16x32_bf16(af[j], bm[i], acc[j][i], 0, 0, 0);
        } else {
            #pragma unroll
            for (int i = 0; i < 4; i++)
                #pragma unroll
                for (int j = 0; j < 4; j++)
                    acc[i][j] = __builtin_amdgcn_mfma_f32_16x16x32_bf16(bm[i], af[j], acc[i][j], 0, 0, 0);
        }
        __syncthreads();
    }

    const int cc = tid & 15, rr = tid >> 4;
    if constexpr (KV == 0) {
        // D[n][m]: n = n0 + wc*64 + j*16 + quad*4 + r, m = m0 + wr*64 + i*16 + lrow
        // stage T[m=128][n=128], ushort4 along n; swizzle chunk ^= (m&7)
        const int n0v = n0 + (wc << 6);
        const int cni = (wc << 3) + (quad >> 1);
        const int ni4 = (quad & 1) << 2;
        #pragma unroll
        for (int j = 0; j < 4; j++) {
            const float* bp = bias + n0v + (j << 4) + (quad << 2);
            float b0 = bp[0], b1 = bp[1], b2 = bp[2], b3 = bp[3];
            #pragma unroll
            for (int i = 0; i < 4; i++) {
                float v0 = acc[j][i][0] + b0, v1 = acc[j][i][1] + b1;
                float v2 = acc[j][i][2] + b2, v3 = acc[j][i][3] + b3;
                v0 = v0 > 0.f ? v0 + 1.f : __expf(v0);
                v1 = v1 > 0.f ? v1 + 1.f : __expf(v1);
                v2 = v2 > 0.f ? v2 + 1.f : __expf(v2);
                v3 = v3 > 0.f ? v3 + 1.f : __expf(v3);
                int ml = (wr << 6) + (i << 4) + lrow;
                int chk = (cni + (j << 1)) ^ (ml & 7);
                *(ushort4*)(smem + ml * 128 + (chk << 3) + ni4) =
                    make_ushort4(f2b(v0), f2b(v1), f2b(v2), f2b(v3));
            }
        }
        __syncthreads();
        const size_t brow = (size_t)b * SS + m0;
        #pragma unroll
        for (int p = 0; p < 8; p++) {
            int ml = (p << 4) + rr;
            bf16x8 vv = *(const bf16x8*)(smem + ml * 128 + ((cc ^ (ml & 7)) << 3));
            *(bf16x8*)(q + (brow + ml) * FF + n0 + (cc << 3)) = vv;
        }
    } else {
        // D[m][n]: m = m0 + wr*64 + i*16 + quad*4 + r (4 consecutive l),
        //          n = n0 + wc*64 + j*16 + lrow
        // stage T[n=128][m=128], ushort4 along m; swizzle chunk ^= (n&7)
        const bool isk = (n0 < 1024);
        unsigned short* outp = isk ? kT : vT;
        const int cmi = (wr << 3) + (quad >> 1);
        const int mi4 = (quad & 1) << 2;
        #pragma unroll
        for (int j = 0; j < 4; j++) {
            const int nl = (wc << 6) + (j << 4) + lrow;
            const float bv = bias[n0 + nl];
            #pragma unroll
            for (int i = 0; i < 4; i++) {
                float v0 = acc[i][j][0] + bv, v1 = acc[i][j][1] + bv;
                float v2 = acc[i][j][2] + bv, v3 = acc[i][j][3] + bv;
                if (isk) {
                    v0 = v0 > 0.f ? v0 + 1.f : __expf(v0);
                    v1 = v1 > 0.f ? v1 + 1.f : __expf(v1);
                    v2 = v2 > 0.f ? v2 + 1.f : __expf(v2);
                    v3 = v3 > 0.f ? v3 + 1.f : __expf(v3);
                }
                int chk = (cmi + (i << 1)) ^ (nl & 7);
                *(ushort4*)(smem + nl * 128 + (chk << 3) + mi4) =
                    make_ushort4(f2b(v0), f2b(v1), f2b(v2), f2b(v3));
            }
        }
        __syncthreads();
        const int nb = n0 & 511;
        #pragma unroll
        for (int p = 0; p < 8; p++) {
            int nl = (p << 4) + rr;
            bf16x8 vv = *(const bf16x8*)(smem + nl * 128 + ((cc ^ (nl & 7)) << 3));
            int nq = nb + nl;
            *(bf16x8*)(outp + (((size_t)b * HH + (nq >> 6)) * DD + (nq & 63)) * SS
                       + m0 + (cc << 3)) = vv;
        }
    }
}

// ---------------------------------------------------------------------------
// kv_mfma: kv[b,h,e,f] += sum_l vT[e][l]*kT[f][l]; ksum[b,h,f] += sum_l kT[f][l]
__global__ __launch_bounds__(256) void kv_mfma(
    const unsigned short* __restrict__ kT, const unsigned short* __restrict__ vT,
    float* __restrict__ kv, float* __restrict__ ksum) {
    const int bh = blockIdx.x;
    const int l0 = blockIdx.y * 512;
    const int tid = threadIdx.x;

    {
        int f = tid >> 2, part = tid & 3;
        const unsigned short* kp = kT + ((size_t)bh * DD + f) * SS + l0 + part * 128;
        float s = 0.f;
        #pragma unroll
        for (int c = 0; c < 16; c++) {
            bf16x8 u = *(const bf16x8*)(kp + c * 8);
            #pragma unroll
            for (int j = 0; j < 8; j++) s += us2f((unsigned short)u[j]);
        }
        s += __shfl_down(s, 1, 64);
        s += __shfl_down(s, 2, 64);
        if (part == 0) atomicAdd(&ksum[bh * DD + f], s);
    }

    const int w = tid >> 6, ln = tid & 63;
    const int lrow = ln & 15, quad = ln >> 4;
    f32x4 acc[4];
    #pragma unroll
    for (int ft = 0; ft < 4; ft++) acc[ft] = (f32x4){0.f, 0.f, 0.f, 0.f};
    const unsigned short* vbase = vT + ((size_t)bh * DD + w * 16 + lrow) * SS + l0;
    const unsigned short* kbase = kT + ((size_t)bh * DD + lrow) * SS + l0;
    for (int ks = 0; ks < 16; ks++) {
        bf16x8 vf = *(const bf16x8*)(vbase + ks * 32 + quad * 8);
        #pragma unroll
        for (int ft = 0; ft < 4; ft++) {
            bf16x8 kf = *(const bf16x8*)(kbase + (size_t)(ft * 16) * SS + ks * 32 + quad * 8);
            acc[ft] = __builtin_amdgcn_mfma_f32_16x16x32_bf16(vf, kf, acc[ft], 0, 0, 0);
        }
    }
    float* kvp = kv + (size_t)bh * 4096;
    #pragma unroll
    for (int ft = 0; ft < 4; ft++) {
        #pragma unroll
        for (int r = 0; r < 4; r++) {
            int e = w * 16 + (quad << 2) + r;
            int f = ft * 16 + lrow;
            atomicAdd(&kvp[e * 64 + f], acc[ft][r]);
        }
    }
}

// ---------------------------------------------------------------------------
__global__ void kvcast(const float* __restrict__ kv, unsigned short* __restrict__ kv16) {
    int i = blockIdx.x * 256 + threadIdx.x;
    float4 v = ((const float4*)kv)[i];
    ((ushort4*)kv16)[i] = make_ushort4(f2b(v.x), f2b(v.y), f2b(v.z), f2b(v.w));
}

// ---------------------------------------------------------------------------
// attn_mfma: attn[b,l,h*64+e] = (sum_f q[l,f]*kv16[e,f]) / (sum_f q[l,f]*ksum[f])
__global__ __launch_bounds__(256) void attn_mfma(
    const unsigned short* __restrict__ q, const unsigned short* __restrict__ kv16,
    const float* __restrict__ ksum, unsigned short* __restrict__ attn) {
    const int bh = blockIdx.y, b = bh >> 3, h = bh & 7;
    const int l0 = blockIdx.x * 128;
    __shared__ float ksS[64];
    __shared__ float zS[128];
    const int tid = threadIdx.x;
    if (tid < 64) ksS[tid] = ksum[bh * DD + tid];
    __syncthreads();
    if (tid < 128) {
        const unsigned short* qp = q + ((size_t)b * SS + l0 + tid) * FF + h * DD;
        float z = 0.f;
        #pragma unroll
        for (int c = 0; c < 8; c++) {
            bf16x8 u = *(const bf16x8*)(qp + c * 8);
            #pragma unroll
            for (int j = 0; j < 8; j++) z += us2f((unsigned short)u[j]) * ksS[c * 8 + j];
        }
        zS[tid] = 1.f / z;
    }
    __syncthreads();

    const int w = tid >> 6, ln = tid & 63;
    const int lrow = ln & 15, quad = ln >> 4;
    const unsigned short* kvp = kv16 + (size_t)bh * 4096;
    bf16x8 kvf[4][2];
    #pragma unroll
    for (int et = 0; et < 4; et++)
        #pragma unroll
        for (int ks = 0; ks < 2; ks++)
            kvf[et][ks] = *(const bf16x8*)(kvp + (et * 16 + lrow) * 64 + ks * 32 + quad * 8);

    f32x4 acc[2][4];
    #pragma unroll
    for (int lt = 0; lt < 2; lt++)
        #pragma unroll
        for (int et = 0; et < 4; et++) acc[lt][et] = (f32x4){0.f, 0.f, 0.f, 0.f};

    const unsigned short* qbase = q + ((size_t)b * SS + l0 + w * 32) * FF + h * DD;
    #pragma unroll
    for (int lt = 0; lt < 2; lt++) {
        #pragma unroll
        for (int ks = 0; ks < 2; ks++) {
            bf16x8 qf = *(const bf16x8*)(qbase + (size_t)(lt * 16 + lrow) * FF + ks * 32 + quad * 8);
            #pragma unroll
            for (int et = 0; et < 4; et++)
                acc[lt][et] = __builtin_amdgcn_mfma_f32_16x16x32_bf16(kvf[et][ks], qf, acc[lt][et], 0, 0, 0);
        }
    }
    #pragma unroll
    for (int lt = 0; lt < 2; lt++) {
        int lloc = w * 32 + lt * 16 + lrow;
        float zi = zS[lloc];
        unsigned short* op = attn + ((size_t)b * SS + l0 + lloc) * FF + h * DD;
        #pragma unroll
        for (int et = 0; et < 4; et++) {
            ushort4 u = make_ushort4(f2b(acc[lt][et][0] * zi), f2b(acc[lt][et][1] * zi),
                                     f2b(acc[lt][et][2] * zi), f2b(acc[lt][et][3] * zi));
            *(ushort4*)(op + et * 16 + (quad << 2)) = u;
        }
    }
}

// ---------------------------------------------------------------------------
// GEMM2, BK=32, normal orientation -> D[m][n]: y[b][n][l] = attn[b][l][:] @ Pb[n][:]
// LDS-staged [n][m] tile -> 256B-row stores; GN2 partial stats fused (registers).
__global__ __launch_bounds__(256) void gemm2_mfma(
    const unsigned short* __restrict__ A, const unsigned short* __restrict__ Bw,
    unsigned short* __restrict__ y, float* __restrict__ gpart) {
    __shared__ unsigned short smem[16384] __attribute__((aligned(16)));  // 32KB
    unsigned short* As = smem;
    unsigned short* Bs = smem + 4096;
    const int b = blockIdx.z;
    const int m0 = blockIdx.x * 128, n0 = blockIdx.y * 128;
    const int tid = threadIdx.x;
    const int w = tid >> 6, ln = tid & 63;
    const int wr = w >> 1, wc = w & 1;
    const int lrow = ln & 15, quad = ln >> 4;

    const int ch0 = tid, ch1 = tid + 256;
    const int ra = ch0 >> 2, ca = ((ch0 & 3) - (ra >> 1)) & 3;
    const int rb = ch1 >> 2, cb = ((ch1 & 3) - (rb >> 1)) & 3;
    const unsigned short* pA0 = A + ((size_t)b * SS + m0 + ra) * FF + ca * 8;
    const unsigned short* pA1 = A + ((size_t)b * SS + m0 + rb) * FF + cb * 8;
    const unsigned short* pB0 = Bw + (size_t)(n0 + ra) * FF + ca * 8;
    const unsigned short* pB1 = Bw + (size_t)(n0 + rb) * FF + cb * 8;
    unsigned short* lA0 = As + ch0 * 8; unsigned short* lA1 = As + ch1 * 8;
    unsigned short* lB0 = Bs + ch0 * 8; unsigned short* lB1 = Bs + ch1 * 8;

    f32x4 acc[4][4];
    #pragma unroll
    for (int i = 0; i < 4; i++)
        #pragma unroll
        for (int j = 0; j < 4; j++) acc[i][j] = (f32x4){0.f, 0.f, 0.f, 0.f};

    for (int kk = 0; kk < 16; kk++) {
        gll16(pA0, lA0); gll16(pA1, lA1); gll16(pB0, lB0); gll16(pB1, lB1);
        pA0 += 32; pA1 += 32; pB0 += 32; pB1 += 32;
        __syncthreads();
        bf16x8 am[4], bn[4];
        #pragma unroll
        for (int i = 0; i < 4; i++) am[i] = fragld(As, wr * 64 + i * 16 + lrow, quad);
        #pragma unroll
        for (int j = 0; j < 4; j++) bn[j] = fragld(Bs, wc * 64 + j * 16 + lrow, quad);
        #pragma unroll
        for (int i = 0; i < 4; i++)
            #pragma unroll
            for (int j = 0; j < 4; j++)
                acc[i][j] = __builtin_amdgcn_mfma_f32_16x16x32_bf16(am[i], bn[j], acc[i][j], 0, 0, 0);
        __syncthreads();
    }
    // D[m][n]: m = m0 + wr*64 + i*16 + quad*4 + r (consecutive l), n = n0 + wc*64 + j*16 + lrow
    // stage T[n=128][m=128], ushort4 along m; swizzle chunk ^= (n&7). GN2 sums pre-staging.
    const int cmi = (wr << 3) + (quad >> 1);
    const int mi4 = (quad & 1) << 2;
    #pragma unroll
    for (int j = 0; j < 4; j++) {
        const int nl = (wc << 6) + (j << 4) + lrow;
        float sj = 0.f, s2j = 0.f;
        #pragma unroll
        for (int i = 0; i < 4; i++) {
            float v0 = acc[i][j][0], v1 = acc[i][j][1], v2 = acc[i][j][2], v3 = acc[i][j][3];
            sj  += v0 + v1 + v2 + v3;
            s2j += v0 * v0 + v1 * v1 + v2 * v2 + v3 * v3;
            int chk = (cmi + (i << 1)) ^ (nl & 7);
            *(ushort4*)(smem + nl * 128 + (chk << 3) + mi4) =
                make_ushort4(f2b(v0), f2b(v1), f2b(v2), f2b(v3));
        }
        #pragma unroll
        for (int off = 32; off > 0; off >>= 1) {
            sj  += __shfl_down(sj, off, 64);
            s2j += __shfl_down(s2j, off, 64);
        }
        if (ln == 0) {
            int g = (n0 + (wc << 6) + (j << 4)) >> 4;
            atomicAdd(&gpart[((b << 5) + g) * 2],     sj);
            atomicAdd(&gpart[((b << 5) + g) * 2 + 1], s2j);
        }
    }
    __syncthreads();
    const int cc = tid & 15, rr = tid >> 4;
    #pragma unroll
    for (int p = 0; p < 8; p++) {
        int nl = (p << 4) + rr;
        bf16x8 vv = *(const bf16x8*)(smem + nl * 128 + ((cc ^ (nl & 7)) << 3));
        *(bf16x8*)(y + ((size_t)b * FF + n0 + nl) * SS + m0 + (cc << 3)) = vv;
    }
}

// ---------------------------------------------------------------------------
__global__ void final_kernel(const float* __restrict__ hid, const bf16* __restrict__ y,
                             const float* __restrict__ gsc, const float* __restrict__ gsh,
                             float* __restrict__ out) {
    int bf = blockIdx.x;
    float a = gsc[bf], c0 = gsh[bf];
    const float4*  hp = (const float4*)(hid + (size_t)bf * SS);
    const ushort4* yp = (const ushort4*)(y + (size_t)bf * SS);
    float4* op = (float4*)(out + (size_t)bf * SS);
    for (int t = threadIdx.x; t < 2048; t += 256) {
        float4 hv = hp[t];
        ushort4 yv = yp[t];
        float4 r;
        r.x = hv.x + a * us2f(yv.x) + c0;
        r.y = hv.y + a * us2f(yv.y) + c0;
        r.z = hv.z + a * us2f(yv.z) + c0;
        r.w = hv.w + a * us2f(yv.w) + c0;
        op[t] = r;
    }
}

// ---------------------------------------------------------------------------
extern "C" void kernel_launch(void* const* d_in, const int* in_sizes, int n_in,
                              void* d_out, int out_size, void* d_ws, size_t ws_size,
                              hipStream_t stream) {
    const float* hid      = (const float*)d_in[0];
    const float* qkv_w    = (const float*)d_in[1];
    const float* qkv_b    = (const float*)d_in[2];
    const float* out_proj = (const float*)d_in[3];
    const float* g1       = (const float*)d_in[4];
    const float* b1       = (const float*)d_in[5];
    const float* g2       = (const float*)d_in[6];
    const float* b2       = (const float*)d_in[7];
    const float* gate     = (const float*)d_in[8];
    float* out = (float*)d_out;

    // workspace layout: attn aliases kT, y aliases vT; xnA lives in d_out
    char* p = (char*)d_ws;
    float* sc1 = (float*)p; p += (size_t)4096 * 4;
    float* sh1 = (float*)p; p += (size_t)4096 * 4;
    float* gsc = (float*)p; p += (size_t)4096 * 4;
    float* gsh = (float*)p; p += (size_t)4096 * 4;
    float* kvb = (float*)p; p += (size_t)262144 * 4;            // [B,H,D,D] fp32 (atomics)
    float* ksm = (float*)p; p += (size_t)4096 * 4;              // [B,H,D] fp32 (atomics)
    float* gnp = (float*)p; p += (size_t)1024 * 4;              // GN partials (2x512)
    unsigned short* kv16 = (unsigned short*)p; p += (size_t)262144 * 2; // bf16 kv
    unsigned short* Wb = (unsigned short*)p; p += (size_t)786432 * 2;   // bf16 [1536,512]
    unsigned short* Pb = (unsigned short*)p; p += (size_t)262144 * 2;   // bf16 [512,512]
    unsigned short* qb = (unsigned short*)p; p += (size_t)33554432 * 2; // [B,S,F]
    unsigned short* kTb = (unsigned short*)p; p += (size_t)33554432 * 2; // [B,H,D,S]
    unsigned short* vTb = (unsigned short*)p;                            // [B,H,D,S]
    unsigned short* attn = kTb;  // alias: kT dead after kv_mfma
    unsigned short* yb   = vTb;  // alias: vT dead after kv_mfma
    unsigned short* xnA  = (unsigned short*)d_out;  // 64MB scratch in d_out

    hipMemsetAsync(kvb, 0, (size_t)(262144 + 4096 + 1024) * 4, stream);

    gn1_part<<<dim3(256, 8), 256, 0, stream>>>(hid, gnp);
    gn_final<<<16, 256, 0, stream>>>(gnp, g1, b1, nullptr, sc1, sh1);
    castb<<<768, 256, 0, stream>>>(qkv_w, Wb, 196608);
    castb<<<256, 256, 0, stream>>>(out_proj, Pb, 65536);
    xn_prep<<<dim3(128, 8, 8), 256, 0, stream>>>(hid, sc1, sh1, xnA);
    gemm1_mfma<0><<<dim3(64, 4, 8), 256, 0, stream>>>(xnA, Wb, qkv_b, qb, kTb, vTb);
    gemm1_mfma<1><<<dim3(64, 8, 8), 256, 0, stream>>>(xnA, Wb, qkv_b, qb, kTb, vTb);
    kv_mfma<<<dim3(64, 16), 256, 0, stream>>>(kTb, vTb, kvb, ksm);
    kvcast<<<256, 256, 0, stream>>>(kvb, kv16);
    attn_mfma<<<dim3(64, 64), 256, 0, stream>>>(qb, kv16, ksm, attn);
    gemm2_mfma<<<dim3(64, 4, 8), 256, 0, stream>>>(attn, Pb, yb, gnp + 512);
    gn_final<<<16, 256, 0, stream>>>(gnp + 512, g2, b2, gate, gsc, gsh);
    final_kernel<<<4096, 256, 0, stream>>>(hid, (const bf16*)yb, gsc, gsh, out);
}

// Round 5
// 623.801 us; speedup vs baseline: 1.1703x; 1.1703x over previous
//
#include <hip/hip_runtime.h>
#include <hip/hip_bf16.h>

// Problem dims
#define BB 8
#define FF 512
#define SS 8192
#define HH 8
#define DD 64
#define N1 1536   // 3*H*D qkv output columns

typedef __hip_bfloat16 bf16;
typedef __attribute__((ext_vector_type(8))) short bf16x8;
typedef __attribute__((ext_vector_type(4))) float f32x4;

__device__ __forceinline__ float us2f(unsigned short u) {
    union { unsigned int i; float f; } x; x.i = ((unsigned int)u) << 16; return x.f;
}
__device__ __forceinline__ unsigned short f2b(float f) {
    unsigned int u = __builtin_bit_cast(unsigned int, f);
    return (unsigned short)((u + 0x7FFFu + ((u >> 16) & 1u)) >> 16);   // RNE
}
__device__ __forceinline__ void gll16(const void* g, void* l) {
    __builtin_amdgcn_global_load_lds((const __attribute__((address_space(1))) void*)g,
                                     (__attribute__((address_space(3))) void*)l, 16, 0, 0);
}
// BK=32 tile: [128 rows][32 bf16], row stride 64B; rotated k-chunk swizzle
__device__ __forceinline__ bf16x8 fragld(const unsigned short* base, int row, int quad) {
    int off = row * 32 + (((quad + (row >> 1)) & 3) << 3);
    return *(const bf16x8*)(base + off);
}

// ---------------------------------------------------------------------------
// GN1 partial stats: grid (256 bg, 8 s-chunks); atomicAdd fp32 partials
__global__ void gn1_part(const float* __restrict__ hid, float* __restrict__ part) {
    int bg = blockIdx.x;
    const float4* base = (const float4*)(hid + ((size_t)(bg >> 5) * FF + (bg & 31) * 16) * SS);
    float s = 0.f, s2 = 0.f;
    int t0 = blockIdx.y * 4096 + threadIdx.x;
    #pragma unroll
    for (int it = 0; it < 16; it++) {
        float4 x = base[t0 + it * 256];
        s  += x.x + x.y + x.z + x.w;
        s2 += x.x * x.x + x.y * x.y + x.z * x.z + x.w * x.w;
    }
    #pragma unroll
    for (int off = 32; off > 0; off >>= 1) {
        s  += __shfl_down(s, off, 64);
        s2 += __shfl_down(s2, off, 64);
    }
    __shared__ float rs_[8];
    int wid = threadIdx.x >> 6, lane = threadIdx.x & 63;
    if (lane == 0) { rs_[wid] = s; rs_[wid + 4] = s2; }
    __syncthreads();
    if (threadIdx.x == 0)
        atomicAdd(&part[bg * 2], rs_[0] + rs_[1] + rs_[2] + rs_[3]);
    else if (threadIdx.x == 64)
        atomicAdd(&part[bg * 2 + 1], rs_[4] + rs_[5] + rs_[6] + rs_[7]);
}

// finalize GN1: per-channel sc/sh
__global__ void gn_final(const float* __restrict__ part, const float* __restrict__ gamma,
                         const float* __restrict__ beta, const float* __restrict__ gate,
                         float* __restrict__ sc, float* __restrict__ sh) {
    int c = blockIdx.x * 256 + threadIdx.x;    // 0..4095  (b*512 + ch)
    int ch = c & 511;
    int bg = (c >> 9) * 32 + (ch >> 4);
    float ts = part[bg * 2], ts2 = part[bg * 2 + 1];
    float mu  = ts * (1.f / 131072.f);
    float var = ts2 * (1.f / 131072.f) - mu * mu;
    float r   = rsqrtf(var + 1e-8f);
    float scv = gamma[ch] * r;
    float shv = beta[ch] - mu * scv;
    if (gate) { float gv = gate[ch]; scv *= gv; shv *= gv; }
    sc[c] = scv; sh[c] = shv;
}

// finalize GN2 from contention-free per-wave partials: 128 slots x (s,s2) per (b,g)
__global__ void gn_final2(const float* __restrict__ part2, const float* __restrict__ gamma,
                          const float* __restrict__ beta, const float* __restrict__ gate,
                          float* __restrict__ sc, float* __restrict__ sh) {
    int c = blockIdx.x * 256 + threadIdx.x;    // 0..4095
    int ch = c & 511;
    int bg = ((c >> 9) << 5) + (ch >> 4);
    const float2* pp = (const float2*)part2 + ((size_t)bg << 7);
    float ts = 0.f, ts2 = 0.f;
    #pragma unroll 8
    for (int i = 0; i < 128; i++) { float2 v = pp[i]; ts += v.x; ts2 += v.y; }
    float mu  = ts * (1.f / 131072.f);
    float var = ts2 * (1.f / 131072.f) - mu * mu;
    float r   = rsqrtf(var + 1e-8f);
    float gv  = gate[ch];
    float scv = gamma[ch] * r;
    sc[c] = gv * scv;
    sh[c] = gv * (beta[ch] - mu * scv);
}

// ---------------------------------------------------------------------------
// elementwise fp32 -> bf16 cast (vectorized x4)
__global__ void castb(const float* __restrict__ s, unsigned short* __restrict__ d, int n4) {
    int i = blockIdx.x * 256 + threadIdx.x;
    if (i >= n4) return;
    float4 v = ((const float4*)s)[i];
    ushort4 u = make_ushort4(f2b(v.x), f2b(v.y), f2b(v.z), f2b(v.w));
    ((ushort4*)d)[i] = u;
}

// ---------------------------------------------------------------------------
// xn_prep: xnA[b][l][f] = bf16( hid[b][f][l]*sc + sh )  (transpose via LDS)
__global__ void xn_prep(const float* __restrict__ hid, const float* __restrict__ sc,
                        const float* __restrict__ sh, unsigned short* __restrict__ xnA) {
    int b = blockIdx.z, f0 = blockIdx.y * 64, l0 = blockIdx.x * 64;
    __shared__ float t[64][65];
    int tid = threadIdx.x;
    #pragma unroll
    for (int it = 0; it < 16; it++) {
        int idx = it * 256 + tid;
        int f = idx >> 6, l = idx & 63;
        int fg = f0 + f;
        t[f][l] = hid[((size_t)b * FF + fg) * SS + l0 + l] * sc[b * FF + fg] + sh[b * FF + fg];
    }
    __syncthreads();
    #pragma unroll
    for (int it = 0; it < 4; it++) {
        int idx = it * 256 + tid;
        int l = idx >> 4, fq = (idx & 15) * 4;
        ushort4 u = make_ushort4(f2b(t[fq + 0][l]), f2b(t[fq + 1][l]),
                                 f2b(t[fq + 2][l]), f2b(t[fq + 3][l]));
        *(ushort4*)(xnA + ((size_t)b * SS + l0 + l) * FF + f0 + fq) = u;
    }
}

// ---------------------------------------------------------------------------
// GEMM1, BK=32, 16 K-steps.
// KV=0: q blocks (n0 = y*128, y<4), swapped MFMA -> D[n][m];
//       staged [m][n] tile (ushort4 writes) -> 256B-row stores into q[B,S,F].
// KV=1: k/v blocks (n0 = 512 + y*128), normal MFMA -> D[m][n];
//       staged [n][m] tile (ushort4 writes) -> 256B-row stores into kT/vT[B,H,D,S].
template<int KV>
__global__ __launch_bounds__(256) void gemm1_mfma(
    const unsigned short* __restrict__ A, const unsigned short* __restrict__ Bw,
    const float* __restrict__ bias,
    unsigned short* __restrict__ q, unsigned short* __restrict__ kT,
    unsigned short* __restrict__ vT) {
    __shared__ unsigned short smem[16384] __attribute__((aligned(16)));  // 32KB
    unsigned short* As = smem;            // 128 x 32
    unsigned short* Bs = smem + 4096;
    const int b = blockIdx.z;
    const int m0 = blockIdx.x * 128;
    const int n0 = (KV ? 512 : 0) + blockIdx.y * 128;
    const int tid = threadIdx.x;
    const int w = tid >> 6, ln = tid & 63;
    const int wr = w >> 1, wc = w & 1;
    const int lrow = ln & 15, quad = ln >> 4;

    const int ch0 = tid, ch1 = tid + 256;
    const int ra = ch0 >> 2, ca = ((ch0 & 3) - (ra >> 1)) & 3;
    const int rb = ch1 >> 2, cb = ((ch1 & 3) - (rb >> 1)) & 3;
    const unsigned short* pA0 = A + ((size_t)b * SS + m0 + ra) * FF + ca * 8;
    const unsigned short* pA1 = A + ((size_t)b * SS + m0 + rb) * FF + cb * 8;
    const unsigned short* pB0 = Bw + (size_t)(n0 + ra) * FF + ca * 8;
    const unsigned short* pB1 = Bw + (size_t)(n0 + rb) * FF + cb * 8;
    unsigned short* lA0 = As + ch0 * 8; unsigned short* lA1 = As + ch1 * 8;
    unsigned short* lB0 = Bs + ch0 * 8; unsigned short* lB1 = Bs + ch1 * 8;

    f32x4 acc[4][4];
    #pragma unroll
    for (int j = 0; j < 4; j++)
        #pragma unroll
        for (int i = 0; i < 4; i++) acc[j][i] = (f32x4){0.f, 0.f, 0.f, 0.f};

    for (int kk = 0; kk < 16; kk++) {
        gll16(pA0, lA0); gll16(pA1, lA1); gll16(pB0, lB0); gll16(pB1, lB1);
        pA0 += 32; pA1 += 32; pB0 += 32; pB1 += 32;
        __syncthreads();
        bf16x8 af[4], bm[4];
        #pragma unroll
        for (int j = 0; j < 4; j++) af[j] = fragld(Bs, wc * 64 + j * 16 + lrow, quad);
        #pragma unroll
        for (int i = 0; i < 4; i++) bm[i] = fragld(As, wr * 64 + i * 16 + lrow, quad);
        if constexpr (KV == 0) {
            #pragma unroll
            for (int j = 0; j < 4; j++)
                #pragma unroll
                for (int i = 0; i < 4; i++)
                    acc[j][i] = __builtin_amdgcn_mfma_f32_16x16x32_bf16(af[j], bm[i], acc[j][i], 0, 0, 0);
        } else {
            #pragma unroll
            for (int i = 0; i < 4; i++)
                #pragma unroll
                for (int j = 0; j < 4; j++)
                    acc[i][j] = __builtin_amdgcn_mfma_f32_16x16x32_bf16(bm[i], af[j], acc[i][j], 0, 0, 0);
        }
        __syncthreads();
    }

    const int cc = tid & 15, rr = tid >> 4;
    if constexpr (KV == 0) {
        // D[n][m]: n = n0 + wc*64 + j*16 + quad*4 + r, m = m0 + wr*64 + i*16 + lrow
        // stage T[m=128][n=128], ushort4 along n; swizzle chunk ^= (m&7)
        const int n0v = n0 + (wc << 6);
        const int cni = (wc << 3) + (quad >> 1);
        const int ni4 = (quad & 1) << 2;
        #pragma unroll
        for (int j = 0; j < 4; j++) {
            const float* bp = bias + n0v + (j << 4) + (quad << 2);
            float b0 = bp[0], b1 = bp[1], b2 = bp[2], b3 = bp[3];
            #pragma unroll
            for (int i = 0; i < 4; i++) {
                float v0 = acc[j][i][0] + b0, v1 = acc[j][i][1] + b1;
                float v2 = acc[j][i][2] + b2, v3 = acc[j][i][3] + b3;
                v0 = v0 > 0.f ? v0 + 1.f : __expf(v0);
                v1 = v1 > 0.f ? v1 + 1.f : __expf(v1);
                v2 = v2 > 0.f ? v2 + 1.f : __expf(v2);
                v3 = v3 > 0.f ? v3 + 1.f : __expf(v3);
                int ml = (wr << 6) + (i << 4) + lrow;
                int chk = (cni + (j << 1)) ^ (ml & 7);
                *(ushort4*)(smem + ml * 128 + (chk << 3) + ni4) =
                    make_ushort4(f2b(v0), f2b(v1), f2b(v2), f2b(v3));
            }
        }
        __syncthreads();
        const size_t brow = (size_t)b * SS + m0;
        #pragma unroll
        for (int p = 0; p < 8; p++) {
            int ml = (p << 4) + rr;
            bf16x8 vv = *(const bf16x8*)(smem + ml * 128 + ((cc ^ (ml & 7)) << 3));
            *(bf16x8*)(q + (brow + ml) * FF + n0 + (cc << 3)) = vv;
        }
    } else {
        // D[m][n]: m = m0 + wr*64 + i*16 + quad*4 + r (4 consecutive l),
        //          n = n0 + wc*64 + j*16 + lrow
        // stage T[n=128][m=128], ushort4 along m; swizzle chunk ^= (n&7)
        const bool isk = (n0 < 1024);
        unsigned short* outp = isk ? kT : vT;
        const int cmi = (wr << 3) + (quad >> 1);
        const int mi4 = (quad & 1) << 2;
        #pragma unroll
        for (int j = 0; j < 4; j++) {
            const int nl = (wc << 6) + (j << 4) + lrow;
            const float bv = bias[n0 + nl];
            #pragma unroll
            for (int i = 0; i < 4; i++) {
                float v0 = acc[i][j][0] + bv, v1 = acc[i][j][1] + bv;
                float v2 = acc[i][j][2] + bv, v3 = acc[i][j][3] + bv;
                if (isk) {
                    v0 = v0 > 0.f ? v0 + 1.f : __expf(v0);
                    v1 = v1 > 0.f ? v1 + 1.f : __expf(v1);
                    v2 = v2 > 0.f ? v2 + 1.f : __expf(v2);
                    v3 = v3 > 0.f ? v3 + 1.f : __expf(v3);
                }
                int chk = (cmi + (i << 1)) ^ (nl & 7);
                *(ushort4*)(smem + nl * 128 + (chk << 3) + mi4) =
                    make_ushort4(f2b(v0), f2b(v1), f2b(v2), f2b(v3));
            }
        }
        __syncthreads();
        const int nb = n0 & 511;
        #pragma unroll
        for (int p = 0; p < 8; p++) {
            int nl = (p << 4) + rr;
            bf16x8 vv = *(const bf16x8*)(smem + nl * 128 + ((cc ^ (nl & 7)) << 3));
            int nq = nb + nl;
            *(bf16x8*)(outp + (((size_t)b * HH + (nq >> 6)) * DD + (nq & 63)) * SS
                       + m0 + (cc << 3)) = vv;
        }
    }
}

// ---------------------------------------------------------------------------
// kv_mfma: kv[b,h,e,f] += sum_l vT[e][l]*kT[f][l] (atomics, low contention);
// ksum partials written contention-free to kpart[bh][lchunk][f].
__global__ __launch_bounds__(256) void kv_mfma(
    const unsigned short* __restrict__ kT, const unsigned short* __restrict__ vT,
    float* __restrict__ kv, float* __restrict__ kpart) {
    const int bh = blockIdx.x;
    const int l0 = blockIdx.y * 512;
    const int tid = threadIdx.x;

    {
        int f = tid >> 2, part = tid & 3;
        const unsigned short* kp = kT + ((size_t)bh * DD + f) * SS + l0 + part * 128;
        float s = 0.f;
        #pragma unroll
        for (int c = 0; c < 16; c++) {
            bf16x8 u = *(const bf16x8*)(kp + c * 8);
            #pragma unroll
            for (int j = 0; j < 8; j++) s += us2f((unsigned short)u[j]);
        }
        s += __shfl_down(s, 1, 64);
        s += __shfl_down(s, 2, 64);
        if (part == 0) kpart[(size_t)bh * 1024 + blockIdx.y * 64 + f] = s;
    }

    const int w = tid >> 6, ln = tid & 63;
    const int lrow = ln & 15, quad = ln >> 4;
    f32x4 acc[4];
    #pragma unroll
    for (int ft = 0; ft < 4; ft++) acc[ft] = (f32x4){0.f, 0.f, 0.f, 0.f};
    const unsigned short* vbase = vT + ((size_t)bh * DD + w * 16 + lrow) * SS + l0;
    const unsigned short* kbase = kT + ((size_t)bh * DD + lrow) * SS + l0;
    for (int ks = 0; ks < 16; ks++) {
        bf16x8 vf = *(const bf16x8*)(vbase + ks * 32 + quad * 8);
        #pragma unroll
        for (int ft = 0; ft < 4; ft++) {
            bf16x8 kf = *(const bf16x8*)(kbase + (size_t)(ft * 16) * SS + ks * 32 + quad * 8);
            acc[ft] = __builtin_amdgcn_mfma_f32_16x16x32_bf16(vf, kf, acc[ft], 0, 0, 0);
        }
    }
    float* kvp = kv + (size_t)bh * 4096;
    #pragma unroll
    for (int ft = 0; ft < 4; ft++) {
        #pragma unroll
        for (int r = 0; r < 4; r++) {
            int e = w * 16 + (quad << 2) + r;
            int f = ft * 16 + lrow;
            atomicAdd(&kvp[e * 64 + f], acc[ft][r]);
        }
    }
}

// ---------------------------------------------------------------------------
// kvcast: fp32 kv -> bf16 kv16; also finalize ksum from the 16 l-chunk partials
__global__ void kvcast(const float* __restrict__ kv, unsigned short* __restrict__ kv16,
                       const float* __restrict__ kpart, float* __restrict__ ksm) {
    int i = blockIdx.x * 256 + threadIdx.x;
    float4 v = ((const float4*)kv)[i];
    ((ushort4*)kv16)[i] = make_ushort4(f2b(v.x), f2b(v.y), f2b(v.z), f2b(v.w));
    if (i < 4096) {            // i = bh*64 + f
        const float* kp = kpart + ((size_t)(i >> 6)) * 1024 + (i & 63);
        float s = 0.f;
        #pragma unroll
        for (int c = 0; c < 16; c++) s += kp[c * 64];
        ksm[i] = s;
    }
}

// ---------------------------------------------------------------------------
// attn_mfma: attn[b,l,h*64+e] = (sum_f q[l,f]*kv16[e,f]) / (sum_f q[l,f]*ksum[f])
__global__ __launch_bounds__(256) void attn_mfma(
    const unsigned short* __restrict__ q, const unsigned short* __restrict__ kv16,
    const float* __restrict__ ksum, unsigned short* __restrict__ attn) {
    const int bh = blockIdx.y, b = bh >> 3, h = bh & 7;
    const int l0 = blockIdx.x * 128;
    __shared__ float ksS[64];
    __shared__ float zS[128];
    const int tid = threadIdx.x;
    if (tid < 64) ksS[tid] = ksum[bh * DD + tid];
    __syncthreads();
    if (tid < 128) {
        const unsigned short* qp = q + ((size_t)b * SS + l0 + tid) * FF + h * DD;
        float z = 0.f;
        #pragma unroll
        for (int c = 0; c < 8; c++) {
            bf16x8 u = *(const bf16x8*)(qp + c * 8);
            #pragma unroll
            for (int j = 0; j < 8; j++) z += us2f((unsigned short)u[j]) * ksS[c * 8 + j];
        }
        zS[tid] = 1.f / z;
    }
    __syncthreads();

    const int w = tid >> 6, ln = tid & 63;
    const int lrow = ln & 15, quad = ln >> 4;
    const unsigned short* kvp = kv16 + (size_t)bh * 4096;
    bf16x8 kvf[4][2];
    #pragma unroll
    for (int et = 0; et < 4; et++)
        #pragma unroll
        for (int ks = 0; ks < 2; ks++)
            kvf[et][ks] = *(const bf16x8*)(kvp + (et * 16 + lrow) * 64 + ks * 32 + quad * 8);

    f32x4 acc[2][4];
    #pragma unroll
    for (int lt = 0; lt < 2; lt++)
        #pragma unroll
        for (int et = 0; et < 4; et++) acc[lt][et] = (f32x4){0.f, 0.f, 0.f, 0.f};

    const unsigned short* qbase = q + ((size_t)b * SS + l0 + w * 32) * FF + h * DD;
    #pragma unroll
    for (int lt = 0; lt < 2; lt++) {
        #pragma unroll
        for (int ks = 0; ks < 2; ks++) {
            bf16x8 qf = *(const bf16x8*)(qbase + (size_t)(lt * 16 + lrow) * FF + ks * 32 + quad * 8);
            #pragma unroll
            for (int et = 0; et < 4; et++)
                acc[lt][et] = __builtin_amdgcn_mfma_f32_16x16x32_bf16(kvf[et][ks], qf, acc[lt][et], 0, 0, 0);
        }
    }
    #pragma unroll
    for (int lt = 0; lt < 2; lt++) {
        int lloc = w * 32 + lt * 16 + lrow;
        float zi = zS[lloc];
        unsigned short* op = attn + ((size_t)b * SS + l0 + lloc) * FF + h * DD;
        #pragma unroll
        for (int et = 0; et < 4; et++) {
            ushort4 u = make_ushort4(f2b(acc[lt][et][0] * zi), f2b(acc[lt][et][1] * zi),
                                     f2b(acc[lt][et][2] * zi), f2b(acc[lt][et][3] * zi));
            *(ushort4*)(op + et * 16 + (quad << 2)) = u;
        }
    }
}

// ---------------------------------------------------------------------------
// GEMM2, BK=32, normal orientation -> D[m][n]: y[b][n][l] = attn[b][l][:] @ Pb[n][:]
// LDS-staged [n][m] tile -> 256B-row stores; GN2 partials written contention-free.
__global__ __launch_bounds__(256) void gemm2_mfma(
    const unsigned short* __restrict__ A, const unsigned short* __restrict__ Bw,
    unsigned short* __restrict__ y, float* __restrict__ gpart2) {
    __shared__ unsigned short smem[16384] __attribute__((aligned(16)));  // 32KB
    unsigned short* As = smem;
    unsigned short* Bs = smem + 4096;
    const int b = blockIdx.z;
    const int m0 = blockIdx.x * 128, n0 = blockIdx.y * 128;
    const int tid = threadIdx.x;
    const int w = tid >> 6, ln = tid & 63;
    const int wr = w >> 1, wc = w & 1;
    const int lrow = ln & 15, quad = ln >> 4;

    const int ch0 = tid, ch1 = tid + 256;
    const int ra = ch0 >> 2, ca = ((ch0 & 3) - (ra >> 1)) & 3;
    const int rb = ch1 >> 2, cb = ((ch1 & 3) - (rb >> 1)) & 3;
    const unsigned short* pA0 = A + ((size_t)b * SS + m0 + ra) * FF + ca * 8;
    const unsigned short* pA1 = A + ((size_t)b * SS + m0 + rb) * FF + cb * 8;
    const unsigned short* pB0 = Bw + (size_t)(n0 + ra) * FF + ca * 8;
    const unsigned short* pB1 = Bw + (size_t)(n0 + rb) * FF + cb * 8;
    unsigned short* lA0 = As + ch0 * 8; unsigned short* lA1 = As + ch1 * 8;
    unsigned short* lB0 = Bs + ch0 * 8; unsigned short* lB1 = Bs + ch1 * 8;

    f32x4 acc[4][4];
    #pragma unroll
    for (int i = 0; i < 4; i++)
        #pragma unroll
        for (int j = 0; j < 4; j++) acc[i][j] = (f32x4){0.f, 0.f, 0.f, 0.f};

    for (int kk = 0; kk < 16; kk++) {
        gll16(pA0, lA0); gll16(pA1, lA1); gll16(pB0, lB0); gll16(pB1, lB1);
        pA0 += 32; pA1 += 32; pB0 += 32; pB1 += 32;
        __syncthreads();
        bf16x8 am[4], bn[4];
        #pragma unroll
        for (int i = 0; i < 4; i++) am[i] = fragld(As, wr * 64 + i * 16 + lrow, quad);
        #pragma unroll
        for (int j = 0; j < 4; j++) bn[j] = fragld(Bs, wc * 64 + j * 16 + lrow, quad);
        #pragma unroll
        for (int i = 0; i < 4; i++)
            #pragma unroll
            for (int j = 0; j < 4; j++)
                acc[i][j] = __builtin_amdgcn_mfma_f32_16x16x32_bf16(am[i], bn[j], acc[i][j], 0, 0, 0);
        __syncthreads();
    }
    // D[m][n]: m = m0 + wr*64 + i*16 + quad*4 + r (consecutive l), n = n0 + wc*64 + j*16 + lrow
    // stage T[n=128][m=128], ushort4 along m; swizzle chunk ^= (n&7). GN2 sums pre-staging.
    const int cmi = (wr << 3) + (quad >> 1);
    const int mi4 = (quad & 1) << 2;
    #pragma unroll
    for (int j = 0; j < 4; j++) {
        const int nl = (wc << 6) + (j << 4) + lrow;
        float sj = 0.f, s2j = 0.f;
        #pragma unroll
        for (int i = 0; i < 4; i++) {
            float v0 = acc[i][j][0], v1 = acc[i][j][1], v2 = acc[i][j][2], v3 = acc[i][j][3];
            sj  += v0 + v1 + v2 + v3;
            s2j += v0 * v0 + v1 * v1 + v2 * v2 + v3 * v3;
            int chk = (cmi + (i << 1)) ^ (nl & 7);
            *(ushort4*)(smem + nl * 128 + (chk << 3) + mi4) =
                make_ushort4(f2b(v0), f2b(v1), f2b(v2), f2b(v3));
        }
        #pragma unroll
        for (int off = 32; off > 0; off >>= 1) {
            sj  += __shfl_down(sj, off, 64);
            s2j += __shfl_down(s2j, off, 64);
        }
        if (ln == 0) {
            int g = (n0 >> 4) + (wc << 2) + j;                       // group 0..31
            size_t slot = ((((size_t)b << 5) + g) << 7) + (blockIdx.x << 1) + wr;
            gpart2[slot * 2]     = sj;
            gpart2[slot * 2 + 1] = s2j;
        }
    }
    __syncthreads();
    const int cc = tid & 15, rr = tid >> 4;
    #pragma unroll
    for (int p = 0; p < 8; p++) {
        int nl = (p << 4) + rr;
        bf16x8 vv = *(const bf16x8*)(smem + nl * 128 + ((cc ^ (nl & 7)) << 3));
        *(bf16x8*)(y + ((size_t)b * FF + n0 + nl) * SS + m0 + (cc << 3)) = vv;
    }
}

// ---------------------------------------------------------------------------
__global__ void final_kernel(const float* __restrict__ hid, const bf16* __restrict__ y,
                             const float* __restrict__ gsc, const float* __restrict__ gsh,
                             float* __restrict__ out) {
    int bf = blockIdx.x;
    float a = gsc[bf], c0 = gsh[bf];
    const float4*  hp = (const float4*)(hid + (size_t)bf * SS);
    const ushort4* yp = (const ushort4*)(y + (size_t)bf * SS);
    float4* op = (float4*)(out + (size_t)bf * SS);
    for (int t = threadIdx.x; t < 2048; t += 256) {
        float4 hv = hp[t];
        ushort4 yv = yp[t];
        float4 r;
        r.x = hv.x + a * us2f(yv.x) + c0;
        r.y = hv.y + a * us2f(yv.y) + c0;
        r.z = hv.z + a * us2f(yv.z) + c0;
        r.w = hv.w + a * us2f(yv.w) + c0;
        op[t] = r;
    }
}

// ---------------------------------------------------------------------------
extern "C" void kernel_launch(void* const* d_in, const int* in_sizes, int n_in,
                              void* d_out, int out_size, void* d_ws, size_t ws_size,
                              hipStream_t stream) {
    const float* hid      = (const float*)d_in[0];
    const float* qkv_w    = (const float*)d_in[1];
    const float* qkv_b    = (const float*)d_in[2];
    const float* out_proj = (const float*)d_in[3];
    const float* g1       = (const float*)d_in[4];
    const float* b1       = (const float*)d_in[5];
    const float* g2       = (const float*)d_in[6];
    const float* b2       = (const float*)d_in[7];
    const float* gate     = (const float*)d_in[8];
    float* out = (float*)d_out;

    // workspace layout: attn aliases kT, y aliases vT; xnA lives in d_out[0,64MB)
    char* p = (char*)d_ws;
    float* sc1 = (float*)p; p += (size_t)4096 * 4;
    float* sh1 = (float*)p; p += (size_t)4096 * 4;
    float* gsc = (float*)p; p += (size_t)4096 * 4;
    float* gsh = (float*)p; p += (size_t)4096 * 4;
    float* kvb = (float*)p; p += (size_t)262144 * 4;            // [B,H,D,D] fp32 (atomics)
    float* ksm = (float*)p; p += (size_t)4096 * 4;              // [B,H,D] fp32
    float* gnp = (float*)p; p += (size_t)1024 * 4;              // GN1 partials
    unsigned short* kv16 = (unsigned short*)p; p += (size_t)262144 * 2; // bf16 kv
    unsigned short* Wb = (unsigned short*)p; p += (size_t)786432 * 2;   // bf16 [1536,512]
    unsigned short* Pb = (unsigned short*)p; p += (size_t)262144 * 2;   // bf16 [512,512]
    unsigned short* qb = (unsigned short*)p; p += (size_t)33554432 * 2; // [B,S,F]
    unsigned short* kTb = (unsigned short*)p; p += (size_t)33554432 * 2; // [B,H,D,S]
    unsigned short* vTb = (unsigned short*)p;                            // [B,H,D,S]
    unsigned short* attn = kTb;  // alias: kT dead after kv_mfma
    unsigned short* yb   = vTb;  // alias: vT dead after kv_mfma
    unsigned short* xnA  = (unsigned short*)d_out;  // 64MB scratch in d_out
    // scratch carved from dead upper half of d_out (read before final_kernel writes)
    float* kpart  = (float*)((char*)d_out + (size_t)64 * 1024 * 1024);           // 256KB [bh][16][64]
    float* gpart2 = (float*)((char*)d_out + (size_t)64 * 1024 * 1024 + 262144);  // 512KB [b*32+g][128][2]

    hipMemsetAsync(kvb, 0, (size_t)(262144 + 4096 + 1024) * 4, stream);

    gn1_part<<<dim3(256, 8), 256, 0, stream>>>(hid, gnp);
    gn_final<<<16, 256, 0, stream>>>(gnp, g1, b1, nullptr, sc1, sh1);
    castb<<<768, 256, 0, stream>>>(qkv_w, Wb, 196608);
    castb<<<256, 256, 0, stream>>>(out_proj, Pb, 65536);
    xn_prep<<<dim3(128, 8, 8), 256, 0, stream>>>(hid, sc1, sh1, xnA);
    gemm1_mfma<0><<<dim3(64, 4, 8), 256, 0, stream>>>(xnA, Wb, qkv_b, qb, kTb, vTb);
    gemm1_mfma<1><<<dim3(64, 8, 8), 256, 0, stream>>>(xnA, Wb, qkv_b, qb, kTb, vTb);
    kv_mfma<<<dim3(64, 16), 256, 0, stream>>>(kTb, vTb, kvb, kpart);
    kvcast<<<256, 256, 0, stream>>>(kvb, kv16, kpart, ksm);
    attn_mfma<<<dim3(64, 64), 256, 0, stream>>>(qb, kv16, ksm, attn);
    gemm2_mfma<<<dim3(64, 4, 8), 256, 0, stream>>>(attn, Pb, yb, gpart2);
    gn_final2<<<16, 256, 0, stream>>>(gpart2, g2, b2, gate, gsc, gsh);
    final_kernel<<<4096, 256, 0, stream>>>(hid, (const bf16*)yb, gsc, gsh, out);
}

// Round 6
// 609.855 us; speedup vs baseline: 1.1970x; 1.0229x over previous
//
#include <hip/hip_runtime.h>
#include <hip/hip_bf16.h>

// Problem dims
#define BB 8
#define FF 512
#define SS 8192
#define HH 8
#define DD 64
#define N1 1536   // 3*H*D qkv output columns

typedef __hip_bfloat16 bf16;
typedef __attribute__((ext_vector_type(8))) short bf16x8;
typedef __attribute__((ext_vector_type(4))) float f32x4;

__device__ __forceinline__ float us2f(unsigned short u) {
    union { unsigned int i; float f; } x; x.i = ((unsigned int)u) << 16; return x.f;
}
__device__ __forceinline__ unsigned short f2b(float f) {
    unsigned int u = __builtin_bit_cast(unsigned int, f);
    return (unsigned short)((u + 0x7FFFu + ((u >> 16) & 1u)) >> 16);   // RNE
}
__device__ __forceinline__ void gll16(const void* g, void* l) {
    __builtin_amdgcn_global_load_lds((const __attribute__((address_space(1))) void*)g,
                                     (__attribute__((address_space(3))) void*)l, 16, 0, 0);
}
// BK=32 tile: [128 rows][32 bf16], row stride 64B; rotated k-chunk swizzle
__device__ __forceinline__ bf16x8 fragld(const unsigned short* base, int row, int quad) {
    int off = row * 32 + (((quad + (row >> 1)) & 3) << 3);
    return *(const bf16x8*)(base + off);
}

// ---------------------------------------------------------------------------
// GN1 partial stats: grid (256 bg, 8 s-chunks); atomicAdd fp32 partials
__global__ void gn1_part(const float* __restrict__ hid, float* __restrict__ part) {
    int bg = blockIdx.x;
    const float4* base = (const float4*)(hid + ((size_t)(bg >> 5) * FF + (bg & 31) * 16) * SS);
    float s = 0.f, s2 = 0.f;
    int t0 = blockIdx.y * 4096 + threadIdx.x;
    #pragma unroll
    for (int it = 0; it < 16; it++) {
        float4 x = base[t0 + it * 256];
        s  += x.x + x.y + x.z + x.w;
        s2 += x.x * x.x + x.y * x.y + x.z * x.z + x.w * x.w;
    }
    #pragma unroll
    for (int off = 32; off > 0; off >>= 1) {
        s  += __shfl_down(s, off, 64);
        s2 += __shfl_down(s2, off, 64);
    }
    __shared__ float rs_[8];
    int wid = threadIdx.x >> 6, lane = threadIdx.x & 63;
    if (lane == 0) { rs_[wid] = s; rs_[wid + 4] = s2; }
    __syncthreads();
    if (threadIdx.x == 0)
        atomicAdd(&part[bg * 2], rs_[0] + rs_[1] + rs_[2] + rs_[3]);
    else if (threadIdx.x == 64)
        atomicAdd(&part[bg * 2 + 1], rs_[4] + rs_[5] + rs_[6] + rs_[7]);
}

// finalize GN1: per-channel sc/sh
__global__ void gn_final(const float* __restrict__ part, const float* __restrict__ gamma,
                         const float* __restrict__ beta, const float* __restrict__ gate,
                         float* __restrict__ sc, float* __restrict__ sh) {
    int c = blockIdx.x * 256 + threadIdx.x;    // 0..4095  (b*512 + ch)
    int ch = c & 511;
    int bg = (c >> 9) * 32 + (ch >> 4);
    float ts = part[bg * 2], ts2 = part[bg * 2 + 1];
    float mu  = ts * (1.f / 131072.f);
    float var = ts2 * (1.f / 131072.f) - mu * mu;
    float r   = rsqrtf(var + 1e-8f);
    float scv = gamma[ch] * r;
    float shv = beta[ch] - mu * scv;
    if (gate) { float gv = gate[ch]; scv *= gv; shv *= gv; }
    sc[c] = scv; sh[c] = shv;
}

// finalize GN2 from contention-free per-wave partials: 128 slots x (s,s2) per (b,g)
__global__ void gn_final2(const float* __restrict__ part2, const float* __restrict__ gamma,
                          const float* __restrict__ beta, const float* __restrict__ gate,
                          float* __restrict__ sc, float* __restrict__ sh) {
    int c = blockIdx.x * 256 + threadIdx.x;    // 0..4095
    int ch = c & 511;
    int bg = ((c >> 9) << 5) + (ch >> 4);
    const float2* pp = (const float2*)part2 + ((size_t)bg << 7);
    float ts = 0.f, ts2 = 0.f;
    #pragma unroll 8
    for (int i = 0; i < 128; i++) { float2 v = pp[i]; ts += v.x; ts2 += v.y; }
    float mu  = ts * (1.f / 131072.f);
    float var = ts2 * (1.f / 131072.f) - mu * mu;
    float r   = rsqrtf(var + 1e-8f);
    float gv  = gate[ch];
    float scv = gamma[ch] * r;
    sc[c] = gv * scv;
    sh[c] = gv * (beta[ch] - mu * scv);
}

// ---------------------------------------------------------------------------
// elementwise fp32 -> bf16 cast (vectorized x4)
__global__ void castb(const float* __restrict__ s, unsigned short* __restrict__ d, int n4) {
    int i = blockIdx.x * 256 + threadIdx.x;
    if (i >= n4) return;
    float4 v = ((const float4*)s)[i];
    ushort4 u = make_ushort4(f2b(v.x), f2b(v.y), f2b(v.z), f2b(v.w));
    ((ushort4*)d)[i] = u;
}

// ---------------------------------------------------------------------------
// xn_prep: xnA[b][l][f] = bf16( hid[b][f][l]*sc + sh )  (transpose via LDS)
__global__ void xn_prep(const float* __restrict__ hid, const float* __restrict__ sc,
                        const float* __restrict__ sh, unsigned short* __restrict__ xnA) {
    int b = blockIdx.z, f0 = blockIdx.y * 64, l0 = blockIdx.x * 64;
    __shared__ float t[64][65];
    int tid = threadIdx.x;
    #pragma unroll
    for (int it = 0; it < 16; it++) {
        int idx = it * 256 + tid;
        int f = idx >> 6, l = idx & 63;
        int fg = f0 + f;
        t[f][l] = hid[((size_t)b * FF + fg) * SS + l0 + l] * sc[b * FF + fg] + sh[b * FF + fg];
    }
    __syncthreads();
    #pragma unroll
    for (int it = 0; it < 4; it++) {
        int idx = it * 256 + tid;
        int l = idx >> 4, fq = (idx & 15) * 4;
        ushort4 u = make_ushort4(f2b(t[fq + 0][l]), f2b(t[fq + 1][l]),
                                 f2b(t[fq + 2][l]), f2b(t[fq + 3][l]));
        *(ushort4*)(xnA + ((size_t)b * SS + l0 + l) * FF + f0 + fq) = u;
    }
}

// ---------------------------------------------------------------------------
// GEMM1-q, BK=32, 16 K-steps: q blocks (n0 = y*128, y<4), swapped MFMA -> D[n][m];
// staged [m][n] tile (ushort4 writes) -> 256B-row stores into q[B,S,F].
__global__ __launch_bounds__(256) void gemm1_q(
    const unsigned short* __restrict__ A, const unsigned short* __restrict__ Bw,
    const float* __restrict__ bias, unsigned short* __restrict__ q) {
    __shared__ unsigned short smem[16384] __attribute__((aligned(16)));  // 32KB
    unsigned short* As = smem;            // 128 x 32
    unsigned short* Bs = smem + 4096;
    const int b = blockIdx.z;
    const int m0 = blockIdx.x * 128;
    const int n0 = blockIdx.y * 128;
    const int tid = threadIdx.x;
    const int w = tid >> 6, ln = tid & 63;
    const int wr = w >> 1, wc = w & 1;
    const int lrow = ln & 15, quad = ln >> 4;

    const int ch0 = tid, ch1 = tid + 256;
    const int ra = ch0 >> 2, ca = ((ch0 & 3) - (ra >> 1)) & 3;
    const int rb = ch1 >> 2, cb = ((ch1 & 3) - (rb >> 1)) & 3;
    const unsigned short* pA0 = A + ((size_t)b * SS + m0 + ra) * FF + ca * 8;
    const unsigned short* pA1 = A + ((size_t)b * SS + m0 + rb) * FF + cb * 8;
    const unsigned short* pB0 = Bw + (size_t)(n0 + ra) * FF + ca * 8;
    const unsigned short* pB1 = Bw + (size_t)(n0 + rb) * FF + cb * 8;
    unsigned short* lA0 = As + ch0 * 8; unsigned short* lA1 = As + ch1 * 8;
    unsigned short* lB0 = Bs + ch0 * 8; unsigned short* lB1 = Bs + ch1 * 8;

    f32x4 acc[4][4];
    #pragma unroll
    for (int j = 0; j < 4; j++)
        #pragma unroll
        for (int i = 0; i < 4; i++) acc[j][i] = (f32x4){0.f, 0.f, 0.f, 0.f};

    for (int kk = 0; kk < 16; kk++) {
        gll16(pA0, lA0); gll16(pA1, lA1); gll16(pB0, lB0); gll16(pB1, lB1);
        pA0 += 32; pA1 += 32; pB0 += 32; pB1 += 32;
        __syncthreads();
        bf16x8 af[4], bm[4];
        #pragma unroll
        for (int j = 0; j < 4; j++) af[j] = fragld(Bs, wc * 64 + j * 16 + lrow, quad);
        #pragma unroll
        for (int i = 0; i < 4; i++) bm[i] = fragld(As, wr * 64 + i * 16 + lrow, quad);
        #pragma unroll
        for (int j = 0; j < 4; j++)
            #pragma unroll
            for (int i = 0; i < 4; i++)
                acc[j][i] = __builtin_amdgcn_mfma_f32_16x16x32_bf16(af[j], bm[i], acc[j][i], 0, 0, 0);
        __syncthreads();
    }

    // D[n][m]: n = n0 + wc*64 + j*16 + quad*4 + r, m = m0 + wr*64 + i*16 + lrow
    // stage T[m=128][n=128], ushort4 along n; swizzle chunk ^= (m&7)
    const int cc = tid & 15, rr = tid >> 4;
    const int n0v = n0 + (wc << 6);
    const int cni = (wc << 3) + (quad >> 1);
    const int ni4 = (quad & 1) << 2;
    #pragma unroll
    for (int j = 0; j < 4; j++) {
        const float* bp = bias + n0v + (j << 4) + (quad << 2);
        float b0 = bp[0], b1 = bp[1], b2 = bp[2], b3 = bp[3];
        #pragma unroll
        for (int i = 0; i < 4; i++) {
            float v0 = acc[j][i][0] + b0, v1 = acc[j][i][1] + b1;
            float v2 = acc[j][i][2] + b2, v3 = acc[j][i][3] + b3;
            v0 = v0 > 0.f ? v0 + 1.f : __expf(v0);
            v1 = v1 > 0.f ? v1 + 1.f : __expf(v1);
            v2 = v2 > 0.f ? v2 + 1.f : __expf(v2);
            v3 = v3 > 0.f ? v3 + 1.f : __expf(v3);
            int ml = (wr << 6) + (i << 4) + lrow;
            int chk = (cni + (j << 1)) ^ (ml & 7);
            *(ushort4*)(smem + ml * 128 + (chk << 3) + ni4) =
                make_ushort4(f2b(v0), f2b(v1), f2b(v2), f2b(v3));
        }
    }
    __syncthreads();
    const size_t brow = (size_t)b * SS + m0;
    #pragma unroll
    for (int p = 0; p < 8; p++) {
        int ml = (p << 4) + rr;
        bf16x8 vv = *(const bf16x8*)(smem + ml * 128 + ((cc ^ (ml & 7)) << 3));
        *(bf16x8*)(q + (brow + ml) * FF + n0 + (cc << 3)) = vv;
    }
}

// ---------------------------------------------------------------------------
// GEMM1-kv FUSED, BK=32: grid (S/128, H, B). Per block: compute k_h (64 cols) and
// v_h (64 cols) for 128 l (normal MFMA -> D[m][n], lane's 4 acc span 4 l).
// Stage tile T[n=128][m=128] in LDS (rows 0..63 = k_h, 64..127 = v_h, cols l),
// then — WITHOUT writing k/v to HBM — compute from the tile:
//   ksum partials: kpart[bh][m0blk][f] = sum_l k (contention-free)
//   kv[bh][e][f] += sum_l v[l][e]*k[l][f]  via 16 MFMAs/wave + atomicAdd
__global__ __launch_bounds__(256) void gemm1_kv(
    const unsigned short* __restrict__ A, const unsigned short* __restrict__ Bw,
    const float* __restrict__ bias,
    float* __restrict__ kv, float* __restrict__ kpart) {
    __shared__ unsigned short smem[16384] __attribute__((aligned(16)));  // 32KB
    unsigned short* As = smem;            // 128 x 32
    unsigned short* Bs = smem + 4096;
    const int b = blockIdx.z;
    const int h = blockIdx.y;
    const int m0 = blockIdx.x * 128;
    const int tid = threadIdx.x;
    const int w = tid >> 6, ln = tid & 63;
    const int wr = w >> 1, wc = w & 1;
    const int lrow = ln & 15, quad = ln >> 4;

    // B rows: tile row r<64 -> k_h = Bw row 512+h*64+r; r>=64 -> v_h = 1024+h*64+(r-64)
    const int ch0 = tid, ch1 = tid + 256;
    const int ra = ch0 >> 2, ca = ((ch0 & 3) - (ra >> 1)) & 3;
    const int rb = ch1 >> 2, cb = ((ch1 & 3) - (rb >> 1)) & 3;
    const int bra = 512 + ((ra >> 6) << 9) + (h << 6) + (ra & 63);
    const int brb = 512 + ((rb >> 6) << 9) + (h << 6) + (rb & 63);
    const unsigned short* pA0 = A + ((size_t)b * SS + m0 + ra) * FF + ca * 8;
    const unsigned short* pA1 = A + ((size_t)b * SS + m0 + rb) * FF + cb * 8;
    const unsigned short* pB0 = Bw + (size_t)bra * FF + ca * 8;
    const unsigned short* pB1 = Bw + (size_t)brb * FF + cb * 8;
    unsigned short* lA0 = As + ch0 * 8; unsigned short* lA1 = As + ch1 * 8;
    unsigned short* lB0 = Bs + ch0 * 8; unsigned short* lB1 = Bs + ch1 * 8;

    f32x4 acc[4][4];
    #pragma unroll
    for (int i = 0; i < 4; i++)
        #pragma unroll
        for (int j = 0; j < 4; j++) acc[i][j] = (f32x4){0.f, 0.f, 0.f, 0.f};

    for (int kk = 0; kk < 16; kk++) {
        gll16(pA0, lA0); gll16(pA1, lA1); gll16(pB0, lB0); gll16(pB1, lB1);
        pA0 += 32; pA1 += 32; pB0 += 32; pB1 += 32;
        __syncthreads();
        bf16x8 af[4], bm[4];
        #pragma unroll
        for (int j = 0; j < 4; j++) af[j] = fragld(Bs, wc * 64 + j * 16 + lrow, quad);
        #pragma unroll
        for (int i = 0; i < 4; i++) bm[i] = fragld(As, wr * 64 + i * 16 + lrow, quad);
        #pragma unroll
        for (int i = 0; i < 4; i++)
            #pragma unroll
            for (int j = 0; j < 4; j++)
                acc[i][j] = __builtin_amdgcn_mfma_f32_16x16x32_bf16(bm[i], af[j], acc[i][j], 0, 0, 0);
        __syncthreads();
    }

    // D[m][n]: m = m0 + wr*64 + i*16 + quad*4 + r (4 consecutive l),
    //          n(tile row) = wc*64 + j*16 + lrow   (k if wc==0, v if wc==1)
    // stage T[n=128][m=128], ushort4 along m; swizzle chunk ^= (n&7)
    const bool isk = (wc == 0);
    const int cmi = (wr << 3) + (quad >> 1);
    const int mi4 = (quad & 1) << 2;
    #pragma unroll
    for (int j = 0; j < 4; j++) {
        const int nl = (wc << 6) + (j << 4) + lrow;
        const int nabs = 512 + ((nl >> 6) << 9) + (h << 6) + (nl & 63);
        const float bv = bias[nabs];
        #pragma unroll
        for (int i = 0; i < 4; i++) {
            float v0 = acc[i][j][0] + bv, v1 = acc[i][j][1] + bv;
            float v2 = acc[i][j][2] + bv, v3 = acc[i][j][3] + bv;
            if (isk) {
                v0 = v0 > 0.f ? v0 + 1.f : __expf(v0);
                v1 = v1 > 0.f ? v1 + 1.f : __expf(v1);
                v2 = v2 > 0.f ? v2 + 1.f : __expf(v2);
                v3 = v3 > 0.f ? v3 + 1.f : __expf(v3);
            }
            int chk = (cmi + (i << 1)) ^ (nl & 7);
            *(ushort4*)(smem + nl * 128 + (chk << 3) + mi4) =
                make_ushort4(f2b(v0), f2b(v1), f2b(v2), f2b(v3));
        }
    }
    __syncthreads();

    // ksum partials: row f = tid>>2 (k rows 0..63), part = tid&3 covers 4 chunks
    {
        int f = tid >> 2, part = tid & 3;
        float s = 0.f;
        #pragma unroll
        for (int c = 0; c < 4; c++) {
            int chk = ((part << 2) + c) ^ (f & 7);
            bf16x8 u = *(const bf16x8*)(smem + f * 128 + (chk << 3));
            #pragma unroll
            for (int jj = 0; jj < 8; jj++) s += us2f((unsigned short)u[jj]);
        }
        s += __shfl_down(s, 1, 64);
        s += __shfl_down(s, 2, 64);
        if (part == 0)
            kpart[(((size_t)(b * HH + h)) * 64 + blockIdx.x) * 64 + f] = s;
    }

    // kv contraction from tile: wave w owns e-rows [w*16, w*16+16); K = 128 l
    f32x4 kacc[4];
    #pragma unroll
    for (int ft = 0; ft < 4; ft++) kacc[ft] = (f32x4){0.f, 0.f, 0.f, 0.f};
    const int vrow = 64 + (w << 4) + lrow;
    #pragma unroll
    for (int ks = 0; ks < 4; ks++) {
        bf16x8 vf = *(const bf16x8*)(smem + vrow * 128 + ((((ks << 2) + quad) ^ (vrow & 7)) << 3));
        #pragma unroll
        for (int ft = 0; ft < 4; ft++) {
            int krow = (ft << 4) + lrow;
            bf16x8 kf = *(const bf16x8*)(smem + krow * 128 + ((((ks << 2) + quad) ^ (krow & 7)) << 3));
            kacc[ft] = __builtin_amdgcn_mfma_f32_16x16x32_bf16(vf, kf, kacc[ft], 0, 0, 0);
        }
    }
    float* kvp = kv + (size_t)(b * HH + h) * 4096;
    #pragma unroll
    for (int ft = 0; ft < 4; ft++) {
        #pragma unroll
        for (int r = 0; r < 4; r++) {
            int e = (w << 4) + (quad << 2) + r;
            int f = (ft << 4) + lrow;
            atomicAdd(&kvp[e * 64 + f], kacc[ft][r]);
        }
    }
}

// ---------------------------------------------------------------------------
// kvcast: fp32 kv -> bf16 kv16; finalize ksum from the 64 m0-block partials
__global__ void kvcast(const float* __restrict__ kv, unsigned short* __restrict__ kv16,
                       const float* __restrict__ kpart, float* __restrict__ ksm) {
    int i = blockIdx.x * 256 + threadIdx.x;
    float4 v = ((const float4*)kv)[i];
    ((ushort4*)kv16)[i] = make_ushort4(f2b(v.x), f2b(v.y), f2b(v.z), f2b(v.w));
    if (i < 4096) {            // i = bh*64 + f
        const float* kp = kpart + ((size_t)(i >> 6)) * 4096 + (i & 63);
        float s = 0.f;
        #pragma unroll 8
        for (int c = 0; c < 64; c++) s += kp[c * 64];
        ksm[i] = s;
    }
}

// ---------------------------------------------------------------------------
// attn_mfma: attn[b,l,h*64+e] = (sum_f q[l,f]*kv16[e,f]) / (sum_f q[l,f]*ksum[f])
__global__ __launch_bounds__(256) void attn_mfma(
    const unsigned short* __restrict__ q, const unsigned short* __restrict__ kv16,
    const float* __restrict__ ksum, unsigned short* __restrict__ attn) {
    const int bh = blockIdx.y, b = bh >> 3, h = bh & 7;
    const int l0 = blockIdx.x * 128;
    __shared__ float ksS[64];
    __shared__ float zS[128];
    const int tid = threadIdx.x;
    if (tid < 64) ksS[tid] = ksum[bh * DD + tid];
    __syncthreads();
    if (tid < 128) {
        const unsigned short* qp = q + ((size_t)b * SS + l0 + tid) * FF + h * DD;
        float z = 0.f;
        #pragma unroll
        for (int c = 0; c < 8; c++) {
            bf16x8 u = *(const bf16x8*)(qp + c * 8);
            #pragma unroll
            for (int j = 0; j < 8; j++) z += us2f((unsigned short)u[j]) * ksS[c * 8 + j];
        }
        zS[tid] = 1.f / z;
    }
    __syncthreads();

    const int w = tid >> 6, ln = tid & 63;
    const int lrow = ln & 15, quad = ln >> 4;
    const unsigned short* kvp = kv16 + (size_t)bh * 4096;
    bf16x8 kvf[4][2];
    #pragma unroll
    for (int et = 0; et < 4; et++)
        #pragma unroll
        for (int ks = 0; ks < 2; ks++)
            kvf[et][ks] = *(const bf16x8*)(kvp + (et * 16 + lrow) * 64 + ks * 32 + quad * 8);

    f32x4 acc[2][4];
    #pragma unroll
    for (int lt = 0; lt < 2; lt++)
        #pragma unroll
        for (int et = 0; et < 4; et++) acc[lt][et] = (f32x4){0.f, 0.f, 0.f, 0.f};

    const unsigned short* qbase = q + ((size_t)b * SS + l0 + w * 32) * FF + h * DD;
    #pragma unroll
    for (int lt = 0; lt < 2; lt++) {
        #pragma unroll
        for (int ks = 0; ks < 2; ks++) {
            bf16x8 qf = *(const bf16x8*)(qbase + (size_t)(lt * 16 + lrow) * FF + ks * 32 + quad * 8);
            #pragma unroll
            for (int et = 0; et < 4; et++)
                acc[lt][et] = __builtin_amdgcn_mfma_f32_16x16x32_bf16(kvf[et][ks], qf, acc[lt][et], 0, 0, 0);
        }
    }
    #pragma unroll
    for (int lt = 0; lt < 2; lt++) {
        int lloc = w * 32 + lt * 16 + lrow;
        float zi = zS[lloc];
        unsigned short* op = attn + ((size_t)b * SS + l0 + lloc) * FF + h * DD;
        #pragma unroll
        for (int et = 0; et < 4; et++) {
            ushort4 u = make_ushort4(f2b(acc[lt][et][0] * zi), f2b(acc[lt][et][1] * zi),
                                     f2b(acc[lt][et][2] * zi), f2b(acc[lt][et][3] * zi));
            *(ushort4*)(op + et * 16 + (quad << 2)) = u;
        }
    }
}

// ---------------------------------------------------------------------------
// GEMM2, BK=32, normal orientation -> D[m][n]: y[b][n][l] = attn[b][l][:] @ Pb[n][:]
// LDS-staged [n][m] tile -> 256B-row stores; GN2 partials written contention-free.
__global__ __launch_bounds__(256) void gemm2_mfma(
    const unsigned short* __restrict__ A, const unsigned short* __restrict__ Bw,
    unsigned short* __restrict__ y, float* __restrict__ gpart2) {
    __shared__ unsigned short smem[16384] __attribute__((aligned(16)));  // 32KB
    unsigned short* As = smem;
    unsigned short* Bs = smem + 4096;
    const int b = blockIdx.z;
    const int m0 = blockIdx.x * 128, n0 = blockIdx.y * 128;
    const int tid = threadIdx.x;
    const int w = tid >> 6, ln = tid & 63;
    const int wr = w >> 1, wc = w & 1;
    const int lrow = ln & 15, quad = ln >> 4;

    const int ch0 = tid, ch1 = tid + 256;
    const int ra = ch0 >> 2, ca = ((ch0 & 3) - (ra >> 1)) & 3;
    const int rb = ch1 >> 2, cb = ((ch1 & 3) - (rb >> 1)) & 3;
    const unsigned short* pA0 = A + ((size_t)b * SS + m0 + ra) * FF + ca * 8;
    const unsigned short* pA1 = A + ((size_t)b * SS + m0 + rb) * FF + cb * 8;
    const unsigned short* pB0 = Bw + (size_t)(n0 + ra) * FF + ca * 8;
    const unsigned short* pB1 = Bw + (size_t)(n0 + rb) * FF + cb * 8;
    unsigned short* lA0 = As + ch0 * 8; unsigned short* lA1 = As + ch1 * 8;
    unsigned short* lB0 = Bs + ch0 * 8; unsigned short* lB1 = Bs + ch1 * 8;

    f32x4 acc[4][4];
    #pragma unroll
    for (int i = 0; i < 4; i++)
        #pragma unroll
        for (int j = 0; j < 4; j++) acc[i][j] = (f32x4){0.f, 0.f, 0.f, 0.f};

    for (int kk = 0; kk < 16; kk++) {
        gll16(pA0, lA0); gll16(pA1, lA1); gll16(pB0, lB0); gll16(pB1, lB1);
        pA0 += 32; pA1 += 32; pB0 += 32; pB1 += 32;
        __syncthreads();
        bf16x8 am[4], bn[4];
        #pragma unroll
        for (int i = 0; i < 4; i++) am[i] = fragld(As, wr * 64 + i * 16 + lrow, quad);
        #pragma unroll
        for (int j = 0; j < 4; j++) bn[j] = fragld(Bs, wc * 64 + j * 16 + lrow, quad);
        #pragma unroll
        for (int i = 0; i < 4; i++)
            #pragma unroll
            for (int j = 0; j < 4; j++)
                acc[i][j] = __builtin_amdgcn_mfma_f32_16x16x32_bf16(am[i], bn[j], acc[i][j], 0, 0, 0);
        __syncthreads();
    }
    // D[m][n]: m = m0 + wr*64 + i*16 + quad*4 + r (consecutive l), n = n0 + wc*64 + j*16 + lrow
    // stage T[n=128][m=128], ushort4 along m; swizzle chunk ^= (n&7). GN2 sums pre-staging.
    const int cmi = (wr << 3) + (quad >> 1);
    const int mi4 = (quad & 1) << 2;
    #pragma unroll
    for (int j = 0; j < 4; j++) {
        const int nl = (wc << 6) + (j << 4) + lrow;
        float sj = 0.f, s2j = 0.f;
        #pragma unroll
        for (int i = 0; i < 4; i++) {
            float v0 = acc[i][j][0], v1 = acc[i][j][1], v2 = acc[i][j][2], v3 = acc[i][j][3];
            sj  += v0 + v1 + v2 + v3;
            s2j += v0 * v0 + v1 * v1 + v2 * v2 + v3 * v3;
            int chk = (cmi + (i << 1)) ^ (nl & 7);
            *(ushort4*)(smem + nl * 128 + (chk << 3) + mi4) =
                make_ushort4(f2b(v0), f2b(v1), f2b(v2), f2b(v3));
        }
        #pragma unroll
        for (int off = 32; off > 0; off >>= 1) {
            sj  += __shfl_down(sj, off, 64);
            s2j += __shfl_down(s2j, off, 64);
        }
        if (ln == 0) {
            int g = (n0 >> 4) + (wc << 2) + j;                       // group 0..31
            size_t slot = ((((size_t)b << 5) + g) << 7) + (blockIdx.x << 1) + wr;
            gpart2[slot * 2]     = sj;
            gpart2[slot * 2 + 1] = s2j;
        }
    }
    __syncthreads();
    const int cc = tid & 15, rr = tid >> 4;
    #pragma unroll
    for (int p = 0; p < 8; p++) {
        int nl = (p << 4) + rr;
        bf16x8 vv = *(const bf16x8*)(smem + nl * 128 + ((cc ^ (nl & 7)) << 3));
        *(bf16x8*)(y + ((size_t)b * FF + n0 + nl) * SS + m0 + (cc << 3)) = vv;
    }
}

// ---------------------------------------------------------------------------
__global__ void final_kernel(const float* __restrict__ hid, const bf16* __restrict__ y,
                             const float* __restrict__ gsc, const float* __restrict__ gsh,
                             float* __restrict__ out) {
    int bf = blockIdx.x;
    float a = gsc[bf], c0 = gsh[bf];
    const float4*  hp = (const float4*)(hid + (size_t)bf * SS);
    const ushort4* yp = (const ushort4*)(y + (size_t)bf * SS);
    float4* op = (float4*)(out + (size_t)bf * SS);
    for (int t = threadIdx.x; t < 2048; t += 256) {
        float4 hv = hp[t];
        ushort4 yv = yp[t];
        float4 r;
        r.x = hv.x + a * us2f(yv.x) + c0;
        r.y = hv.y + a * us2f(yv.y) + c0;
        r.z = hv.z + a * us2f(yv.z) + c0;
        r.w = hv.w + a * us2f(yv.w) + c0;
        op[t] = r;
    }
}

// ---------------------------------------------------------------------------
extern "C" void kernel_launch(void* const* d_in, const int* in_sizes, int n_in,
                              void* d_out, int out_size, void* d_ws, size_t ws_size,
                              hipStream_t stream) {
    const float* hid      = (const float*)d_in[0];
    const float* qkv_w    = (const float*)d_in[1];
    const float* qkv_b    = (const float*)d_in[2];
    const float* out_proj = (const float*)d_in[3];
    const float* g1       = (const float*)d_in[4];
    const float* b1       = (const float*)d_in[5];
    const float* g2       = (const float*)d_in[6];
    const float* b2       = (const float*)d_in[7];
    const float* gate     = (const float*)d_in[8];
    float* out = (float*)d_out;

    // workspace layout: xnA lives in d_out[0,64MB); attn/y use ws big buffers
    char* p = (char*)d_ws;
    float* sc1 = (float*)p; p += (size_t)4096 * 4;
    float* sh1 = (float*)p; p += (size_t)4096 * 4;
    float* gsc = (float*)p; p += (size_t)4096 * 4;
    float* gsh = (float*)p; p += (size_t)4096 * 4;
    float* kvb = (float*)p; p += (size_t)262144 * 4;            // [B,H,D,D] fp32 (atomics)
    float* ksm = (float*)p; p += (size_t)4096 * 4;              // [B,H,D] fp32
    float* gnp = (float*)p; p += (size_t)1024 * 4;              // GN1 partials
    unsigned short* kv16 = (unsigned short*)p; p += (size_t)262144 * 2; // bf16 kv
    unsigned short* Wb = (unsigned short*)p; p += (size_t)786432 * 2;   // bf16 [1536,512]
    unsigned short* Pb = (unsigned short*)p; p += (size_t)262144 * 2;   // bf16 [512,512]
    unsigned short* qb = (unsigned short*)p; p += (size_t)33554432 * 2; // [B,S,F]
    unsigned short* attn = (unsigned short*)p; p += (size_t)33554432 * 2; // [B,S,F]
    unsigned short* yb   = (unsigned short*)p;                            // [B,F,S]
    unsigned short* xnA  = (unsigned short*)d_out;  // 64MB scratch in d_out
    // scratch carved from dead upper half of d_out (read before final_kernel writes)
    float* kpart  = (float*)((char*)d_out + (size_t)64 * 1024 * 1024);            // 1MB [bh][64][64]
    float* gpart2 = (float*)((char*)d_out + (size_t)64 * 1024 * 1024 + 1048576);  // 512KB [b*32+g][128][2]

    hipMemsetAsync(kvb, 0, (size_t)(262144 + 4096 + 1024) * 4, stream);

    gn1_part<<<dim3(256, 8), 256, 0, stream>>>(hid, gnp);
    gn_final<<<16, 256, 0, stream>>>(gnp, g1, b1, nullptr, sc1, sh1);
    castb<<<768, 256, 0, stream>>>(qkv_w, Wb, 196608);
    castb<<<256, 256, 0, stream>>>(out_proj, Pb, 65536);
    xn_prep<<<dim3(128, 8, 8), 256, 0, stream>>>(hid, sc1, sh1, xnA);
    gemm1_q<<<dim3(64, 4, 8), 256, 0, stream>>>(xnA, Wb, qkv_b, qb);
    gemm1_kv<<<dim3(64, 8, 8), 256, 0, stream>>>(xnA, Wb, qkv_b, kvb, kpart);
    kvcast<<<256, 256, 0, stream>>>(kvb, kv16, kpart, ksm);
    attn_mfma<<<dim3(64, 64), 256, 0, stream>>>(qb, kv16, ksm, attn);
    gemm2_mfma<<<dim3(64, 4, 8), 256, 0, stream>>>(attn, Pb, yb, gpart2);
    gn_final2<<<16, 256, 0, stream>>>(gpart2, g2, b2, gate, gsc, gsh);
    final_kernel<<<4096, 256, 0, stream>>>(hid, (const bf16*)yb, gsc, gsh, out);
}